// Round 1
// baseline (1865.641 us; speedup 1.0000x reference)
//
#include <hip/hip_runtime.h>
#include <hip/hip_bf16.h>
#include <math.h>

// Problem constants (B=1)
#define S_LEN 2048
#define HDIM  4096
#define NH    32
#define NKV   8
#define HD    128
#define KVD   (NKV * HD)   // 1024

typedef int   v4i __attribute__((ext_vector_type(4)));
typedef float v4f __attribute__((ext_vector_type(4)));
typedef short v8s __attribute__((ext_vector_type(8)));

__device__ __forceinline__ short f32_bf16(float f) {
  unsigned u = __builtin_bit_cast(unsigned, f);
  u = (u + 0x7FFFu + ((u >> 16) & 1u)) >> 16;   // RNE
  return (short)u;
}

__device__ __forceinline__ int quant1(float x, float inv) {
  float q = rintf(x * inv);                      // round-half-even, matches jnp.round
  q = fminf(fmaxf(q, -128.0f), 127.0f);
  return (int)q;
}

// ---------------- RoPE cos/sin tables [S][64] ----------------
__global__ void k_rope_tables(float* __restrict__ ct, float* __restrict__ st) {
  int idx = blockIdx.x * 256 + threadIdx.x;
  if (idx >= S_LEN * 64) return;
  int s = idx >> 6, d = idx & 63;
  float ex = (float)(2 * d) * (1.0f / 128.0f);
  float inv = 1.0f / powf(10000.0f, ex);
  float f = (float)s * inv;
  ct[idx] = cosf(f);
  st[idx] = sinf(f);
}

// ---------------- per-row fake-quant: f32 [R][4096] -> i8 + scale ----------------
__global__ __launch_bounds__(256) void k_quant_rows(const float* __restrict__ src,
                                                    signed char* __restrict__ dst,
                                                    float* __restrict__ scales) {
  int r = blockIdx.x;
  const float* x = src + (size_t)r * HDIM;
  int t = threadIdx.x;
  float4 v[4];
  float am = 0.f;
#pragma unroll
  for (int i = 0; i < 4; ++i) {
    v[i] = ((const float4*)x)[i * 256 + t];
    am = fmaxf(am, fmaxf(fmaxf(fabsf(v[i].x), fabsf(v[i].y)),
                         fmaxf(fabsf(v[i].z), fabsf(v[i].w))));
  }
#pragma unroll
  for (int m = 1; m < 64; m <<= 1) am = fmaxf(am, __shfl_xor(am, m));
  __shared__ float red[4];
  if ((t & 63) == 0) red[t >> 6] = am;
  __syncthreads();
  am = fmaxf(fmaxf(red[0], red[1]), fmaxf(red[2], red[3]));
  float s = fmaxf(am * (1.0f / 127.0f), 1e-8f);
  float inv = 1.0f / s;
  if (t == 0) scales[r] = s;
  int* out = (int*)(dst + (size_t)r * HDIM);
#pragma unroll
  for (int i = 0; i < 4; ++i) {
    unsigned p = (unsigned)(quant1(v[i].x, inv) & 255)
               | ((unsigned)(quant1(v[i].y, inv) & 255) << 8)
               | ((unsigned)(quant1(v[i].z, inv) & 255) << 16)
               | ((unsigned)(quant1(v[i].w, inv) & 255) << 24);
    out[i * 256 + t] = (int)p;
  }
}

// ---------------- exact i8 GEMM + dequant: C[M][N] = (A @ B^T) * sa[m]*sb[n] ----------------
// A [M][4096] i8 row-major, B [N][4096] i8 row-major. BM=128 (4 waves x 32 rows), BN=128.
__global__ __launch_bounds__(256) void k_gemm_i8(const signed char* __restrict__ A,
                                                 const float* __restrict__ sa,
                                                 const signed char* __restrict__ B,
                                                 const float* __restrict__ sb,
                                                 float* __restrict__ C, int N) {
  const int K = HDIM;
  int lane = threadIdx.x & 63;
  int w = threadIdx.x >> 6;
  int m0 = blockIdx.y * 128 + w * 32;
  int n0 = blockIdx.x * 128;
  const signed char* arow = A + (size_t)(m0 + (lane & 15)) * K + ((lane >> 4) * 8);
  const signed char* brow = B + (size_t)(n0 + (lane & 15)) * K + ((lane >> 4) * 8);
  v4i acc[2][8];
  v4i zi = {0, 0, 0, 0};
#pragma unroll
  for (int mt = 0; mt < 2; ++mt)
#pragma unroll
    for (int nt = 0; nt < 8; ++nt) acc[mt][nt] = zi;

  for (int k0 = 0; k0 < K; k0 += 32) {
    long a0 = *(const long*)(arow + k0);
    long a1 = *(const long*)(arow + (size_t)16 * K + k0);
#pragma unroll
    for (int nt = 0; nt < 8; ++nt) {
      long b = *(const long*)(brow + (size_t)nt * 16 * K + k0);
      acc[0][nt] = __builtin_amdgcn_mfma_i32_16x16x32_i8(a0, b, acc[0][nt], 0, 0, 0);
      acc[1][nt] = __builtin_amdgcn_mfma_i32_16x16x32_i8(a1, b, acc[1][nt], 0, 0, 0);
    }
  }
  // C/D layout: col = lane&15, row = (lane>>4)*4 + reg   [guide §3, m89-verified]
  int crow = (lane >> 4) * 4;
  int ccol = lane & 15;
#pragma unroll
  for (int mt = 0; mt < 2; ++mt)
#pragma unroll
    for (int r = 0; r < 4; ++r) {
      int m = m0 + mt * 16 + crow + r;
      float sam = sa[m];
      float* cp = C + (size_t)m * N + n0;
#pragma unroll
      for (int nt = 0; nt < 8; ++nt) {
        int n = nt * 16 + ccol;
        cp[n] = (float)acc[mt][nt][r] * sam * sb[n0 + n];
      }
    }
}

// ---------------- RoPE + per-128 fake-quant, layout [nh][S][HD] ----------------
__global__ void k_rope_quant(const float* __restrict__ src, const float* __restrict__ ct,
                             const float* __restrict__ st, signed char* __restrict__ dst,
                             float* __restrict__ scales, int nh) {
  int b = blockIdx.x;
  int h = b >> 11;                 // / S_LEN
  int s = b & (S_LEN - 1);
  int d = threadIdx.x;             // 0..63
  size_t base = (size_t)s * ((size_t)nh * HD) + (size_t)h * HD;
  float x1 = src[base + d];
  float x2 = src[base + d + 64];
  float c = ct[(s << 6) + d], sn = st[(s << 6) + d];
  float o1 = x1 * c - x2 * sn;
  float o2 = x2 * c + x1 * sn;
  float am = fmaxf(fabsf(o1), fabsf(o2));
#pragma unroll
  for (int m = 1; m < 64; m <<= 1) am = fmaxf(am, __shfl_xor(am, m));
  float sc = fmaxf(am * (1.0f / 127.0f), 1e-8f);
  float inv = 1.0f / sc;
  if (d == 0) scales[h * S_LEN + s] = sc;
  signed char* o = dst + ((size_t)h * S_LEN + s) * HD;
  o[d] = (signed char)quant1(o1, inv);
  o[d + 64] = (signed char)quant1(o2, inv);
}

// ---------------- V: per-128 fake-quant, store integers as bf16 TRANSPOSED [NKV][HD][S] ----------------
__global__ void k_quant_v(const float* __restrict__ Vf, short* __restrict__ vt,
                          float* __restrict__ sv) {
  int b = blockIdx.x;
  int hk = b >> 11;
  int s = b & (S_LEN - 1);
  int d = threadIdx.x;
  size_t base = (size_t)s * KVD + (size_t)hk * HD;
  float x1 = Vf[base + d];
  float x2 = Vf[base + d + 64];
  float am = fmaxf(fabsf(x1), fabsf(x2));
#pragma unroll
  for (int m = 1; m < 64; m <<= 1) am = fmaxf(am, __shfl_xor(am, m));
  float sc = fmaxf(am * (1.0f / 127.0f), 1e-8f);
  float inv = 1.0f / sc;
  if (d == 0) sv[hk * S_LEN + s] = sc;
  int q1i = quant1(x1, inv), q2i = quant1(x2, inv);
  size_t vb = (size_t)hk * HD * S_LEN;
  vt[vb + (size_t)d * S_LEN + s] = f32_bf16((float)q1i);          // exact: |int|<=128
  vt[vb + (size_t)(d + 64) * S_LEN + s] = f32_bf16((float)q2i);
}

// ---------------- attention: two-pass (exact row-max), exact i8 QK^T, bf16 PV ----------------
// grid (S/64, NH), 4 waves; wave w owns q rows q0+16w..+15.
__global__ __launch_bounds__(256) void k_attn(const signed char* __restrict__ qi8,
                                              const float* __restrict__ sq,
                                              const signed char* __restrict__ ki8,
                                              const float* __restrict__ sk,
                                              const short* __restrict__ vt,
                                              const float* __restrict__ sv,
                                              float* __restrict__ out) {
  int qt = blockIdx.x;
  int h = blockIdx.y;
  int hk = h >> 2;
  int lane = threadIdx.x & 63;
  int w = threadIdx.x >> 6;
  int q0 = qt * 64;
  int wrow0 = q0 + w * 16;

  const signed char* qbase = qi8 + (size_t)h * S_LEN * HD;
  const signed char* kbase = ki8 + (size_t)hk * S_LEN * HD;
  const short* vbase = vt + (size_t)hk * HD * S_LEN;
  const float* skh = sk + hk * S_LEN;
  const float* svh = sv + hk * S_LEN;

  // A-fragments (q) for 4 k-slices of 32: lane holds row lane&15, bytes ks*32+(lane>>4)*8
  long aq[4];
  {
    const signed char* qrow = qbase + (size_t)(wrow0 + (lane & 15)) * HD + ((lane >> 4) * 8);
#pragma unroll
    for (int ks = 0; ks < 4; ++ks) aq[ks] = *(const long*)(qrow + ks * 32);
  }
  int crow = (lane >> 4) * 4;
  int ccol = lane & 15;
  float sq_r[4];
#pragma unroll
  for (int r = 0; r < 4; ++r)
    sq_r[r] = sq[h * S_LEN + wrow0 + crow + r] * 0.08838834764831843f;  // fold 1/sqrt(128)

  int ntiles = qt + 1;
  float mrow[4] = {-3e38f, -3e38f, -3e38f, -3e38f};

  // PASS 1: exact row max
  for (int jt = 0; jt < ntiles; ++jt) {
    int j0 = jt * 64;
#pragma unroll
    for (int nt = 0; nt < 4; ++nt) {
      int jc = j0 + nt * 16;
      const signed char* krow = kbase + (size_t)(jc + (lane & 15)) * HD + ((lane >> 4) * 8);
      v4i acc = {0, 0, 0, 0};
#pragma unroll
      for (int ks = 0; ks < 4; ++ks) {
        long b = *(const long*)(krow + ks * 32);
        acc = __builtin_amdgcn_mfma_i32_16x16x32_i8(aq[ks], b, acc, 0, 0, 0);
      }
      int j = jc + ccol;
      float skj = skh[j];
#pragma unroll
      for (int r = 0; r < 4; ++r) {
        if (j <= wrow0 + crow + r) {
          float scv = (float)acc[r] * sq_r[r] * skj;
          mrow[r] = fmaxf(mrow[r], scv);
        }
      }
    }
  }
#pragma unroll
  for (int r = 0; r < 4; ++r) {
    float v = mrow[r];
    v = fmaxf(v, __shfl_xor(v, 1));
    v = fmaxf(v, __shfl_xor(v, 2));
    v = fmaxf(v, __shfl_xor(v, 4));
    v = fmaxf(v, __shfl_xor(v, 8));
    mrow[r] = v;
  }

  // PASS 2: pi = rint(127 e^{s-m}); Z accumulate; PV via bf16 MFMA
  __shared__ short wlds[4][1024];  // per wave [16 rows][64 kv], XOR-swizzled (+16B per row&7)
  float Z[4] = {0.f, 0.f, 0.f, 0.f};
  v4f accp[8];
  v4f zf = {0.f, 0.f, 0.f, 0.f};
#pragma unroll
  for (int dt = 0; dt < 8; ++dt) accp[dt] = zf;

  for (int jt = 0; jt < ntiles; ++jt) {
    int j0 = jt * 64;
#pragma unroll
    for (int nt = 0; nt < 4; ++nt) {
      int jc = j0 + nt * 16;
      const signed char* krow = kbase + (size_t)(jc + (lane & 15)) * HD + ((lane >> 4) * 8);
      v4i acc = {0, 0, 0, 0};
#pragma unroll
      for (int ks = 0; ks < 4; ++ks) {
        long b = *(const long*)(krow + ks * 32);
        acc = __builtin_amdgcn_mfma_i32_16x16x32_i8(aq[ks], b, acc, 0, 0, 0);
      }
      int j = jc + ccol;
      float skj = skh[j];
      float svj = svh[j];
#pragma unroll
      for (int r = 0; r < 4; ++r) {
        int row = crow + r;
        float e = 0.f;
        if (j <= wrow0 + row) {
          float scv = (float)acc[r] * sq_r[r] * skj;
          e = expf(scv - mrow[r]);
        }
        Z[r] += e;
        float pv = rintf(127.0f * e);
        float wv = pv * svj;               // P-integer * V-row-scale (bf16: only approx step)
        int idx = (row << 6) | (nt * 16 + ccol);
        idx ^= (row & 7) << 3;             // bank swizzle at 16B granularity
        wlds[w][idx] = f32_bf16(wv);
      }
    }
    __syncthreads();  // intra-wave LDS visibility insurance; ntiles is block-uniform
#pragma unroll
    for (int ks2 = 0; ks2 < 2; ++ks2) {
      int base = ((lane & 15) << 6) + ks2 * 32 + ((lane >> 4) * 8);
      base ^= (lane & 7) << 3;
      v8s aw = *(const v8s*)&wlds[w][base];
      const short* vp = vbase + j0 + ks2 * 32 + ((lane >> 4) * 8) + (size_t)(lane & 15) * S_LEN;
#pragma unroll
      for (int dt = 0; dt < 8; ++dt) {
        v8s bv = *(const v8s*)(vp + (size_t)dt * 16 * S_LEN);
        accp[dt] = __builtin_amdgcn_mfma_f32_16x16x32_bf16(aw, bv, accp[dt], 0, 0, 0);
      }
    }
    __syncthreads();  // protect wlds rewrite next iteration
  }

#pragma unroll
  for (int r = 0; r < 4; ++r) {
    float v = Z[r];
    v += __shfl_xor(v, 1);
    v += __shfl_xor(v, 2);
    v += __shfl_xor(v, 4);
    v += __shfl_xor(v, 8);
    Z[r] = v;
  }
#pragma unroll
  for (int dt = 0; dt < 8; ++dt)
#pragma unroll
    for (int r = 0; r < 4; ++r) {
      int i = wrow0 + crow + r;
      int d = dt * 16 + ccol;
      out[(size_t)i * HDIM + (size_t)h * HD + d] = accp[dt][r] / (127.0f * Z[r]);
    }
}

// ------------------------------------------------------------------
extern "C" void kernel_launch(void* const* d_in, const int* in_sizes, int n_in,
                              void* d_out, int out_size, void* d_ws, size_t ws_size,
                              hipStream_t stream) {
  const float* x  = (const float*)d_in[0];
  // d_in[1] attention_mask: causal, applied analytically. d_in[2] position_ids: arange.
  const float* Wq = (const float*)d_in[3];
  const float* Wk = (const float*)d_in[4];
  const float* Wv = (const float*)d_in[5];
  const float* Wo = (const float*)d_in[6];

  char* p = (char*)d_ws;
  auto alloc = [&](size_t sz) { char* r = p; p += (sz + 255) & ~(size_t)255; return r; };
  signed char* QX  = (signed char*)alloc((size_t)S_LEN * HDIM);      // 8 MiB
  float* SX        = (float*)alloc(S_LEN * 4);
  signed char* WQI = (signed char*)alloc((size_t)HDIM * HDIM);       // 16 MiB
  float* SWQ       = (float*)alloc(HDIM * 4);
  signed char* WKI = (signed char*)alloc((size_t)KVD * HDIM);        // 4 MiB
  float* SWK       = (float*)alloc(KVD * 4);
  signed char* WVI = (signed char*)alloc((size_t)KVD * HDIM);        // 4 MiB
  float* SWV       = (float*)alloc(KVD * 4);
  signed char* WOI = (signed char*)alloc((size_t)HDIM * HDIM);       // 16 MiB
  float* SWO       = (float*)alloc(HDIM * 4);
  float* QF        = (float*)alloc((size_t)S_LEN * HDIM * 4);        // 32 MiB
  float* KF        = (float*)alloc((size_t)S_LEN * KVD * 4);         // 8 MiB
  float* VF        = (float*)alloc((size_t)S_LEN * KVD * 4);         // 8 MiB
  signed char* QI8 = (signed char*)alloc((size_t)NH * S_LEN * HD);   // 8 MiB
  float* SQ        = (float*)alloc(NH * S_LEN * 4);
  signed char* KI8 = (signed char*)alloc((size_t)NKV * S_LEN * HD);  // 2 MiB
  float* SK        = (float*)alloc(NKV * S_LEN * 4);
  short* VT        = (short*)alloc((size_t)NKV * HD * S_LEN * 2);    // 4 MiB
  float* SV        = (float*)alloc(NKV * S_LEN * 4);
  float* CT        = (float*)alloc(S_LEN * 64 * 4);
  float* ST        = (float*)alloc(S_LEN * 64 * 4);
  float* SA        = (float*)alloc(S_LEN * 4);
  // aliases (lifetimes disjoint): attn output reuses QF; attn-quant i8 reuses QX
  float* ATTNF       = QF;
  signed char* AI8   = QX;

  k_rope_tables<<<(S_LEN * 64 + 255) / 256, 256, 0, stream>>>(CT, ST);

  k_quant_rows<<<S_LEN, 256, 0, stream>>>(x, QX, SX);
  k_quant_rows<<<HDIM, 256, 0, stream>>>(Wq, WQI, SWQ);
  k_quant_rows<<<KVD, 256, 0, stream>>>(Wk, WKI, SWK);
  k_quant_rows<<<KVD, 256, 0, stream>>>(Wv, WVI, SWV);
  k_quant_rows<<<HDIM, 256, 0, stream>>>(Wo, WOI, SWO);

  k_gemm_i8<<<dim3(HDIM / 128, S_LEN / 128), 256, 0, stream>>>(QX, SX, WQI, SWQ, QF, HDIM);
  k_gemm_i8<<<dim3(KVD / 128, S_LEN / 128), 256, 0, stream>>>(QX, SX, WKI, SWK, KF, KVD);
  k_gemm_i8<<<dim3(KVD / 128, S_LEN / 128), 256, 0, stream>>>(QX, SX, WVI, SWV, VF, KVD);

  k_rope_quant<<<NH * S_LEN, 64, 0, stream>>>(QF, CT, ST, QI8, SQ, NH);
  k_rope_quant<<<NKV * S_LEN, 64, 0, stream>>>(KF, CT, ST, KI8, SK, NKV);
  k_quant_v<<<NKV * S_LEN, 64, 0, stream>>>(VF, VT, SV);

  k_attn<<<dim3(S_LEN / 64, NH), 256, 0, stream>>>(QI8, SQ, KI8, SK, VT, SV, ATTNF);

  k_quant_rows<<<S_LEN, 256, 0, stream>>>(ATTNF, AI8, SA);
  k_gemm_i8<<<dim3(HDIM / 128, S_LEN / 128), 256, 0, stream>>>(AI8, SA, WOI, SWO,
                                                               (float*)d_out, HDIM);
}

// Round 2
// 634.378 us; speedup vs baseline: 2.9409x; 2.9409x over previous
//
#include <hip/hip_runtime.h>
#include <hip/hip_bf16.h>
#include <math.h>

// Problem constants (B=1)
#define S_LEN 2048
#define HDIM  4096
#define NH    32
#define NKV   8
#define HD    128
#define KVD   (NKV * HD)   // 1024

typedef int   v4i __attribute__((ext_vector_type(4)));
typedef float v4f __attribute__((ext_vector_type(4)));
typedef short v8s __attribute__((ext_vector_type(8)));

// async global->LDS, 16B per lane; LDS dest = wave-uniform base + lane*16
#define GLL16(g, l) \
  __builtin_amdgcn_global_load_lds((__attribute__((address_space(1))) void*)(g), \
                                   (__attribute__((address_space(3))) void*)(l), 16, 0, 0)

__device__ __forceinline__ short f32_bf16(float f) {
  unsigned u = __builtin_bit_cast(unsigned, f);
  u = (u + 0x7FFFu + ((u >> 16) & 1u)) >> 16;   // RNE
  return (short)u;
}

__device__ __forceinline__ int quant1(float x, float inv) {
  float q = rintf(x * inv);                      // round-half-even, matches jnp.round
  q = fminf(fmaxf(q, -128.0f), 127.0f);
  return (int)q;
}

// ---------------- RoPE cos/sin tables [S][64] ----------------
__global__ void k_rope_tables(float* __restrict__ ct, float* __restrict__ st) {
  int idx = blockIdx.x * 256 + threadIdx.x;
  if (idx >= S_LEN * 64) return;
  int s = idx >> 6, d = idx & 63;
  float ex = (float)(2 * d) * (1.0f / 128.0f);
  float inv = 1.0f / powf(10000.0f, ex);
  float f = (float)s * inv;
  ct[idx] = cosf(f);
  st[idx] = sinf(f);
}

// ---------------- per-row fake-quant: f32 [R][4096] -> i8 + scale ----------------
__global__ __launch_bounds__(256) void k_quant_rows(const float* __restrict__ src,
                                                    signed char* __restrict__ dst,
                                                    float* __restrict__ scales) {
  int r = blockIdx.x;
  const float* x = src + (size_t)r * HDIM;
  int t = threadIdx.x;
  float4 v[4];
  float am = 0.f;
#pragma unroll
  for (int i = 0; i < 4; ++i) {
    v[i] = ((const float4*)x)[i * 256 + t];
    am = fmaxf(am, fmaxf(fmaxf(fabsf(v[i].x), fabsf(v[i].y)),
                         fmaxf(fabsf(v[i].z), fabsf(v[i].w))));
  }
#pragma unroll
  for (int m = 1; m < 64; m <<= 1) am = fmaxf(am, __shfl_xor(am, m));
  __shared__ float red[4];
  if ((t & 63) == 0) red[t >> 6] = am;
  __syncthreads();
  am = fmaxf(fmaxf(red[0], red[1]), fmaxf(red[2], red[3]));
  float s = fmaxf(am * (1.0f / 127.0f), 1e-8f);
  float inv = 1.0f / s;
  if (t == 0) scales[r] = s;
  int* out = (int*)(dst + (size_t)r * HDIM);
#pragma unroll
  for (int i = 0; i < 4; ++i) {
    unsigned p = (unsigned)(quant1(v[i].x, inv) & 255)
               | ((unsigned)(quant1(v[i].y, inv) & 255) << 8)
               | ((unsigned)(quant1(v[i].z, inv) & 255) << 16)
               | ((unsigned)(quant1(v[i].w, inv) & 255) << 24);
    out[i * 256 + t] = (int)p;
  }
}

// ---------------- i8 GEMM, m97-style 2-phase LDS pipeline ----------------
// C[M][N] = (A @ B^T) * sa[m]*sb[n]; A [M][4096] i8, B [N][4096] i8, both row-major.
// BK=64 bytes; LDS tiles [rows][64B] with chunk swizzle phys_off = off ^ ((row&3)<<4).
// MTC = m-tiles(16) per wave: 4 -> BM=128, 2 -> BM=64. BN=128 always, waves 2x2.
template <int MTC>
__device__ __forceinline__ void gemm_body(const signed char* __restrict__ A,
                                          const float* __restrict__ sa,
                                          const signed char* __restrict__ B,
                                          const float* __restrict__ sb,
                                          float* __restrict__ C, int N, int m0, int n0,
                                          signed char* Al, signed char* Bl) {
  const int K = HDIM;
  int lane = threadIdx.x & 63, w = threadIdx.x >> 6;
  int wrb = (w >> 1) * (MTC * 16);   // wave row base in tile
  int wcb = (w & 1) * 64;            // wave col base in tile
  int srow = lane >> 2;                                  // staging: 4 lanes per 64B row
  int schunk = (((lane & 3) ^ ((lane >> 2) & 3)) << 4);  // pre-swizzled source chunk
  constexpr int ACH = MTC * 2;   // A 1KB-chunks per tile (8 or 4)
  constexpr int APW = ACH / 4;   // per wave (2 or 1)

  v4i acc[MTC][4];
  v4i zi = {0, 0, 0, 0};
#pragma unroll
  for (int mt = 0; mt < MTC; ++mt)
#pragma unroll
    for (int nt = 0; nt < 4; ++nt) acc[mt][nt] = zi;

  auto stage = [&](int buf, int k0) {
#pragma unroll
    for (int i = 0; i < APW; ++i) {
      int idx = w * APW + i;
      int row = idx * 16 + srow;
      GLL16(A + (size_t)(m0 + row) * K + k0 + schunk, Al + buf * 8192 + idx * 1024);
    }
#pragma unroll
    for (int i = 0; i < 2; ++i) {
      int idx = w * 2 + i;
      int row = idx * 16 + srow;
      GLL16(B + (size_t)(n0 + row) * K + k0 + schunk, Bl + buf * 8192 + idx * 1024);
    }
  };

  stage(0, 0);
  __syncthreads();   // full drain: buf0 staged
  int cur = 0;
  const int nk = K / 64;
  for (int t = 0; t < nk; ++t) {
    if (t + 1 < nk) stage(cur ^ 1, (t + 1) * 64);   // issue next-tile loads first
    const signed char* Ab = Al + cur * 8192;
    const signed char* Bb = Bl + cur * 8192;
#pragma unroll
    for (int ks = 0; ks < 2; ++ks) {
      int foff = ks * 32 + ((lane >> 4) * 8);
      long af[MTC], bf[4];
#pragma unroll
      for (int mt = 0; mt < MTC; ++mt) {
        int row = wrb + mt * 16 + (lane & 15);
        af[mt] = *(const long*)(Ab + row * 64 + (foff ^ ((row & 3) << 4)));
      }
#pragma unroll
      for (int nt = 0; nt < 4; ++nt) {
        int row = wcb + nt * 16 + (lane & 15);
        bf[nt] = *(const long*)(Bb + row * 64 + (foff ^ ((row & 3) << 4)));
      }
#pragma unroll
      for (int mt = 0; mt < MTC; ++mt)
#pragma unroll
        for (int nt = 0; nt < 4; ++nt)
          acc[mt][nt] = __builtin_amdgcn_mfma_i32_16x16x32_i8(af[mt], bf[nt], acc[mt][nt], 0, 0, 0);
    }
    __syncthreads();   // readers done + next buf staged (vmcnt drained by barrier)
    cur ^= 1;
  }

  int crow = (lane >> 4) * 4, ccol = lane & 15;
  float sbv[4];
#pragma unroll
  for (int nt = 0; nt < 4; ++nt) sbv[nt] = sb[n0 + wcb + nt * 16 + ccol];
#pragma unroll
  for (int mt = 0; mt < MTC; ++mt)
#pragma unroll
    for (int r = 0; r < 4; ++r) {
      int m = m0 + wrb + mt * 16 + crow + r;
      float sam = sa[m];
      float* cp = C + (size_t)m * N + n0 + wcb;
#pragma unroll
      for (int nt = 0; nt < 4; ++nt)
        cp[nt * 16 + ccol] = (float)acc[mt][nt][r] * sam * sbv[nt];
    }
}

__global__ __launch_bounds__(256) void k_gemm128(const signed char* __restrict__ A,
                                                 const float* __restrict__ sa,
                                                 const signed char* __restrict__ B,
                                                 const float* __restrict__ sb,
                                                 float* __restrict__ C, int N) {
  __shared__ signed char Al[2][8192];
  __shared__ signed char Bl[2][8192];
  gemm_body<4>(A, sa, B, sb, C, N, blockIdx.y * 128, blockIdx.x * 128, &Al[0][0], &Bl[0][0]);
}

// fused K+V projection: grid (16, M/64); bx<8 -> K, else V. BM=64.
__global__ __launch_bounds__(256) void k_gemm_kv(const signed char* __restrict__ A,
                                                 const float* __restrict__ sa,
                                                 const signed char* __restrict__ Bk,
                                                 const float* __restrict__ sbk,
                                                 float* __restrict__ Ck,
                                                 const signed char* __restrict__ Bv,
                                                 const float* __restrict__ sbv,
                                                 float* __restrict__ Cv) {
  __shared__ signed char Al[2][8192];
  __shared__ signed char Bl[2][8192];
  int bx = blockIdx.x;
  if (bx < 8)
    gemm_body<2>(A, sa, Bk, sbk, Ck, KVD, blockIdx.y * 64, bx * 128, &Al[0][0], &Bl[0][0]);
  else
    gemm_body<2>(A, sa, Bv, sbv, Cv, KVD, blockIdx.y * 64, (bx - 8) * 128, &Al[0][0], &Bl[0][0]);
}

// ---------------- RoPE + per-128 fake-quant, layout [nh][S][HD] ----------------
__global__ void k_rope_quant(const float* __restrict__ src, const float* __restrict__ ct,
                             const float* __restrict__ st, signed char* __restrict__ dst,
                             float* __restrict__ scales, int nh) {
  int b = blockIdx.x;
  int h = b >> 11;                 // / S_LEN
  int s = b & (S_LEN - 1);
  int d = threadIdx.x;             // 0..63
  size_t base = (size_t)s * ((size_t)nh * HD) + (size_t)h * HD;
  float x1 = src[base + d];
  float x2 = src[base + d + 64];
  float c = ct[(s << 6) + d], sn = st[(s << 6) + d];
  float o1 = x1 * c - x2 * sn;
  float o2 = x2 * c + x1 * sn;
  float am = fmaxf(fabsf(o1), fabsf(o2));
#pragma unroll
  for (int m = 1; m < 64; m <<= 1) am = fmaxf(am, __shfl_xor(am, m));
  float sc = fmaxf(am * (1.0f / 127.0f), 1e-8f);
  float inv = 1.0f / sc;
  if (d == 0) scales[h * S_LEN + s] = sc;
  signed char* o = dst + ((size_t)h * S_LEN + s) * HD;
  o[d] = (signed char)quant1(o1, inv);
  o[d + 64] = (signed char)quant1(o2, inv);
}

// ---------------- V: per-128 fake-quant, integers as bf16, TRANSPOSED [NKV][HD][S] ----------------
__global__ void k_quant_v(const float* __restrict__ Vf, short* __restrict__ vt,
                          float* __restrict__ sv) {
  int b = blockIdx.x;
  int hk = b >> 11;
  int s = b & (S_LEN - 1);
  int d = threadIdx.x;
  size_t base = (size_t)s * KVD + (size_t)hk * HD;
  float x1 = Vf[base + d];
  float x2 = Vf[base + d + 64];
  float am = fmaxf(fabsf(x1), fabsf(x2));
#pragma unroll
  for (int m = 1; m < 64; m <<= 1) am = fmaxf(am, __shfl_xor(am, m));
  float sc = fmaxf(am * (1.0f / 127.0f), 1e-8f);
  float inv = 1.0f / sc;
  if (d == 0) sv[hk * S_LEN + s] = sc;
  int q1i = quant1(x1, inv), q2i = quant1(x2, inv);
  size_t vb = (size_t)hk * HD * S_LEN;
  vt[vb + (size_t)d * S_LEN + s] = f32_bf16((float)q1i);          // exact: |int|<=128
  vt[vb + (size_t)(d + 64) * S_LEN + s] = f32_bf16((float)q2i);
}

// ---------------- attention: two-pass, LDS-staged K/V, balanced grid ----------------
// grid (NH, 32); by -> qt via paired map so each CU's 4 blocks sum to 66 tiles.
// 4 waves; wave w owns q rows q0+16w..+15. K tile 64x128B, V tile 128x128B in LDS,
// both staged via global_load_lds with pre-swizzled source (phys = off ^ ((row&7)<<4)).
__global__ __launch_bounds__(256, 4) void k_attn(const signed char* __restrict__ qi8,
                                                 const float* __restrict__ sq,
                                                 const signed char* __restrict__ ki8,
                                                 const float* __restrict__ sk,
                                                 const short* __restrict__ vt,
                                                 const float* __restrict__ sv,
                                                 float* __restrict__ out) {
  int h = blockIdx.x;
  int by = blockIdx.y;
  int qt = (by < 16) ? by : 47 - by;   // pairing: CU's blocks {b,b+8,31-b,23-b} -> 66 tiles
  int hk = h >> 2;
  int lane = threadIdx.x & 63;
  int w = threadIdx.x >> 6;
  int q0 = qt * 64;
  int wrow0 = q0 + w * 16;

  __shared__ signed char Klds[64 * 128];   // 8 KiB
  __shared__ short Vlds[128 * 64];         // 16 KiB, [d][s_local]
  __shared__ short wlds[4][1024];          // 8 KiB, per-wave P*sv tile

  const signed char* qbase = qi8 + (size_t)h * S_LEN * HD;
  const signed char* kbase = ki8 + (size_t)hk * S_LEN * HD;
  const short* vbase = vt + (size_t)hk * HD * S_LEN;
  const float* skh = sk + hk * S_LEN;
  const float* svh = sv + hk * S_LEN;

  // Q fragments: lane holds row lane&15, bytes ks*32+(lane>>4)*8
  long aq[4];
  {
    const signed char* qrow = qbase + (size_t)(wrow0 + (lane & 15)) * HD + ((lane >> 4) * 8);
#pragma unroll
    for (int ks = 0; ks < 4; ++ks) aq[ks] = *(const long*)(qrow + ks * 32);
  }
  int crow = (lane >> 4) * 4;
  int ccol = lane & 15;
  float sq2[4];
#pragma unroll
  for (int r = 0; r < 4; ++r)   // fold 1/sqrt(128) and log2(e): use exp2 downstream
    sq2[r] = sq[h * S_LEN + wrow0 + crow + r] *
             (0.08838834764831843f * 1.4426950408889634f);

  int ntiles = qt + 1;
  int srow = lane >> 3;                                  // staging: 8 lanes per 128B row
  int schunk = (((lane & 7) ^ ((lane >> 3) & 7)) << 4);  // pre-swizzled source chunk

  // PASS 1: exact row max of base-2-scaled scores
  float mrow[4] = {-3e38f, -3e38f, -3e38f, -3e38f};
  for (int jt = 0; jt < ntiles; ++jt) {
    int j0 = jt * 64;
    __syncthreads();   // previous tile's LDS reads done
#pragma unroll
    for (int i = 0; i < 2; ++i) {
      int idx = w * 2 + i;
      int row = idx * 8 + srow;
      GLL16(kbase + (size_t)(j0 + row) * HD + schunk, Klds + idx * 1024);
    }
    __syncthreads();   // staging complete (barrier drains vmcnt)
#pragma unroll
    for (int nt = 0; nt < 4; ++nt) {
      int jr = nt * 16 + ccol;
      const signed char* kr = Klds + jr * 128;
      v4i acc = {0, 0, 0, 0};
#pragma unroll
      for (int ks = 0; ks < 4; ++ks) {
        long b = *(const long*)(kr + ((ks * 32 + ((lane >> 4) * 8)) ^ ((jr & 7) << 4)));
        acc = __builtin_amdgcn_mfma_i32_16x16x32_i8(aq[ks], b, acc, 0, 0, 0);
      }
      int j = j0 + jr;
      float skj = skh[j];
#pragma unroll
      for (int r = 0; r < 4; ++r)
        if (j <= wrow0 + crow + r)
          mrow[r] = fmaxf(mrow[r], (float)acc[r] * sq2[r] * skj);
    }
  }
#pragma unroll
  for (int r = 0; r < 4; ++r) {
    float v = mrow[r];
    v = fmaxf(v, __shfl_xor(v, 1));
    v = fmaxf(v, __shfl_xor(v, 2));
    v = fmaxf(v, __shfl_xor(v, 4));
    v = fmaxf(v, __shfl_xor(v, 8));
    mrow[r] = v;
  }

  // PASS 2: p_int = rint(127*2^(s2-m2)); Z accumulate; PV via bf16 MFMA
  float Z[4] = {0.f, 0.f, 0.f, 0.f};
  v4f accp[8];
  v4f zf = {0.f, 0.f, 0.f, 0.f};
#pragma unroll
  for (int dt = 0; dt < 8; ++dt) accp[dt] = zf;

  for (int jt = 0; jt < ntiles; ++jt) {
    int j0 = jt * 64;
    __syncthreads();
#pragma unroll
    for (int i = 0; i < 2; ++i) {
      int idx = w * 2 + i;
      int row = idx * 8 + srow;
      GLL16(kbase + (size_t)(j0 + row) * HD + schunk, Klds + idx * 1024);
    }
#pragma unroll
    for (int i = 0; i < 4; ++i) {
      int idx = w * 4 + i;
      int row = idx * 8 + srow;
      GLL16((const char*)vbase + (size_t)row * (S_LEN * 2) + (size_t)j0 * 2 + schunk,
            (char*)Vlds + idx * 1024);
    }
    __syncthreads();
#pragma unroll
    for (int nt = 0; nt < 4; ++nt) {
      int jr = nt * 16 + ccol;
      const signed char* kr = Klds + jr * 128;
      v4i acc = {0, 0, 0, 0};
#pragma unroll
      for (int ks = 0; ks < 4; ++ks) {
        long b = *(const long*)(kr + ((ks * 32 + ((lane >> 4) * 8)) ^ ((jr & 7) << 4)));
        acc = __builtin_amdgcn_mfma_i32_16x16x32_i8(aq[ks], b, acc, 0, 0, 0);
      }
      int j = j0 + jr;
      float skj = skh[j];
      float svj = svh[j];
#pragma unroll
      for (int r = 0; r < 4; ++r) {
        int row = crow + r;
        float e = 0.f;
        if (j <= wrow0 + row) e = exp2f((float)acc[r] * sq2[r] * skj - mrow[r]);
        Z[r] += e;
        float wv = rintf(127.0f * e) * svj;   // P-integer * V-row-scale (bf16 approx step)
        int idx = (row << 6) | (nt * 16 + ccol);
        idx ^= (row & 7) << 3;                // element swizzle (16B granularity)
        wlds[w][idx] = f32_bf16(wv);
      }
    }
    // PV: A from wlds (per-wave, same-wave lgkm ordering), B from Vlds
#pragma unroll
    for (int ks2 = 0; ks2 < 2; ++ks2) {
      int bels = ((lane & 15) << 6) + ks2 * 32 + ((lane >> 4) * 8);
      bels ^= (lane & 7) << 3;
      v8s aw = *(const v8s*)&wlds[w][bels];
#pragma unroll
      for (int dt = 0; dt < 8; ++dt) {
        int d = dt * 16 + (lane & 15);
        int off = (ks2 * 64 + ((lane >> 4) << 4)) ^ ((d & 7) << 4);
        v8s bv = *(const v8s*)((const char*)Vlds + d * 128 + off);
        accp[dt] = __builtin_amdgcn_mfma_f32_16x16x32_bf16(aw, bv, accp[dt], 0, 0, 0);
      }
    }
  }

#pragma unroll
  for (int r = 0; r < 4; ++r) {
    float v = Z[r];
    v += __shfl_xor(v, 1);
    v += __shfl_xor(v, 2);
    v += __shfl_xor(v, 4);
    v += __shfl_xor(v, 8);
    Z[r] = 1.0f / (127.0f * v);
  }
#pragma unroll
  for (int dt = 0; dt < 8; ++dt)
#pragma unroll
    for (int r = 0; r < 4; ++r) {
      int i = wrow0 + crow + r;
      int d = dt * 16 + ccol;
      out[(size_t)i * HDIM + (size_t)h * HD + d] = accp[dt][r] * Z[r];
    }
}

// ------------------------------------------------------------------
extern "C" void kernel_launch(void* const* d_in, const int* in_sizes, int n_in,
                              void* d_out, int out_size, void* d_ws, size_t ws_size,
                              hipStream_t stream) {
  const float* x  = (const float*)d_in[0];
  // d_in[1] attention_mask: causal, applied analytically. d_in[2] position_ids: arange.
  const float* Wq = (const float*)d_in[3];
  const float* Wk = (const float*)d_in[4];
  const float* Wv = (const float*)d_in[5];
  const float* Wo = (const float*)d_in[6];

  char* p = (char*)d_ws;
  auto alloc = [&](size_t sz) { char* r = p; p += (sz + 255) & ~(size_t)255; return r; };
  signed char* QX  = (signed char*)alloc((size_t)S_LEN * HDIM);      // 8 MiB
  float* SX        = (float*)alloc(S_LEN * 4);
  signed char* WQI = (signed char*)alloc((size_t)HDIM * HDIM);       // 16 MiB
  float* SWQ       = (float*)alloc(HDIM * 4);
  signed char* WKI = (signed char*)alloc((size_t)KVD * HDIM);        // 4 MiB
  float* SWK       = (float*)alloc(KVD * 4);
  signed char* WVI = (signed char*)alloc((size_t)KVD * HDIM);        // 4 MiB
  float* SWV       = (float*)alloc(KVD * 4);
  signed char* WOI = (signed char*)alloc((size_t)HDIM * HDIM);       // 16 MiB
  float* SWO       = (float*)alloc(HDIM * 4);
  float* QF        = (float*)alloc((size_t)S_LEN * HDIM * 4);        // 32 MiB
  float* KF        = (float*)alloc((size_t)S_LEN * KVD * 4);         // 8 MiB
  float* VF        = (float*)alloc((size_t)S_LEN * KVD * 4);         // 8 MiB
  signed char* QI8 = (signed char*)alloc((size_t)NH * S_LEN * HD);   // 8 MiB
  float* SQ        = (float*)alloc(NH * S_LEN * 4);
  signed char* KI8 = (signed char*)alloc((size_t)NKV * S_LEN * HD);  // 2 MiB
  float* SK        = (float*)alloc(NKV * S_LEN * 4);
  short* VT        = (short*)alloc((size_t)NKV * HD * S_LEN * 2);    // 4 MiB
  float* SV        = (float*)alloc(NKV * S_LEN * 4);
  float* CT        = (float*)alloc(S_LEN * 64 * 4);
  float* ST        = (float*)alloc(S_LEN * 64 * 4);
  float* SA        = (float*)alloc(S_LEN * 4);
  // aliases (lifetimes disjoint): attn output reuses QF; attn-quant i8 reuses QX
  float* ATTNF     = QF;
  signed char* AI8 = QX;

  k_rope_tables<<<(S_LEN * 64 + 255) / 256, 256, 0, stream>>>(CT, ST);

  k_quant_rows<<<S_LEN, 256, 0, stream>>>(x, QX, SX);
  k_quant_rows<<<HDIM, 256, 0, stream>>>(Wq, WQI, SWQ);
  k_quant_rows<<<KVD, 256, 0, stream>>>(Wk, WKI, SWK);
  k_quant_rows<<<KVD, 256, 0, stream>>>(Wv, WVI, SWV);
  k_quant_rows<<<HDIM, 256, 0, stream>>>(Wo, WOI, SWO);

  k_gemm128<<<dim3(HDIM / 128, S_LEN / 128), 256, 0, stream>>>(QX, SX, WQI, SWQ, QF, HDIM);
  k_gemm_kv<<<dim3(16, S_LEN / 64), 256, 0, stream>>>(QX, SX, WKI, SWK, KF, WVI, SWV, VF);

  k_rope_quant<<<NH * S_LEN, 64, 0, stream>>>(QF, CT, ST, QI8, SQ, NH);
  k_rope_quant<<<NKV * S_LEN, 64, 0, stream>>>(KF, CT, ST, KI8, SK, NKV);
  k_quant_v<<<NKV * S_LEN, 64, 0, stream>>>(VF, VT, SV);

  k_attn<<<dim3(NH, 32), 256, 0, stream>>>(QI8, SQ, KI8, SK, VT, SV, ATTNF);

  k_quant_rows<<<S_LEN, 256, 0, stream>>>(ATTNF, AI8, SA);
  k_gemm128<<<dim3(HDIM / 128, S_LEN / 128), 256, 0, stream>>>(AI8, SA, WOI, SWO,
                                                               (float*)d_out, HDIM);
}

// Round 4
// 494.500 us; speedup vs baseline: 3.7728x; 1.2829x over previous
//
#include <hip/hip_runtime.h>
#include <hip/hip_bf16.h>
#include <math.h>

// Problem constants (B=1)
#define S_LEN 2048
#define HDIM  4096
#define NH    32
#define NKV   8
#define HD    128
#define KVD   (NKV * HD)     // 1024
#define QKVN  6144           // 4096 (Q) + 1024 (K) + 1024 (V) fused projection cols

typedef int   v4i  __attribute__((ext_vector_type(4)));
typedef int   v16i __attribute__((ext_vector_type(16)));
typedef float v4f  __attribute__((ext_vector_type(4)));
typedef short v8s  __attribute__((ext_vector_type(8)));

// async global->LDS, 16B per lane; LDS dest = wave-uniform base + lane*16
#define GLL16(g, l) \
  __builtin_amdgcn_global_load_lds((__attribute__((address_space(1))) void*)(g), \
                                   (__attribute__((address_space(3))) void*)(l), 16, 0, 0)

__device__ __forceinline__ short f32_bf16(float f) {
  unsigned u = __builtin_bit_cast(unsigned, f);
  u = (u + 0x7FFFu + ((u >> 16) & 1u)) >> 16;   // RNE
  return (short)u;
}

__device__ __forceinline__ int quant1(float x, float inv) {
  float q = rintf(x * inv);                      // round-half-even, matches jnp.round
  q = fminf(fmaxf(q, -128.0f), 127.0f);
  return (int)q;
}

// ---------------- RoPE cos/sin tables [S][64] ----------------
__global__ void k_rope_tables(float* __restrict__ ct, float* __restrict__ st) {
  int idx = blockIdx.x * 256 + threadIdx.x;
  if (idx >= S_LEN * 64) return;
  int s = idx >> 6, d = idx & 63;
  float ex = (float)(2 * d) * (1.0f / 128.0f);
  float inv = 1.0f / powf(10000.0f, ex);
  float f = (float)s * inv;
  ct[idx] = cosf(f);
  st[idx] = sinf(f);
}

// ---------------- per-row fake-quant: f32 [R][4096] -> i8 + scale ----------------
__global__ __launch_bounds__(256) void k_quant_rows(const float* __restrict__ src,
                                                    signed char* __restrict__ dst,
                                                    float* __restrict__ scales) {
  int r = blockIdx.x;
  const float* x = src + (size_t)r * HDIM;
  int t = threadIdx.x;
  float4 v[4];
  float am = 0.f;
#pragma unroll
  for (int i = 0; i < 4; ++i) {
    v[i] = ((const float4*)x)[i * 256 + t];
    am = fmaxf(am, fmaxf(fmaxf(fabsf(v[i].x), fabsf(v[i].y)),
                         fmaxf(fabsf(v[i].z), fabsf(v[i].w))));
  }
#pragma unroll
  for (int m = 1; m < 64; m <<= 1) am = fmaxf(am, __shfl_xor(am, m));
  __shared__ float red[4];
  if ((t & 63) == 0) red[t >> 6] = am;
  __syncthreads();
  am = fmaxf(fmaxf(red[0], red[1]), fmaxf(red[2], red[3]));
  float s = fmaxf(am * (1.0f / 127.0f), 1e-8f);
  float inv = 1.0f / s;
  if (t == 0) scales[r] = s;
  int* out = (int*)(dst + (size_t)r * HDIM);
#pragma unroll
  for (int i = 0; i < 4; ++i) {
    unsigned p = (unsigned)(quant1(v[i].x, inv) & 255)
               | ((unsigned)(quant1(v[i].y, inv) & 255) << 8)
               | ((unsigned)(quant1(v[i].z, inv) & 255) << 16)
               | ((unsigned)(quant1(v[i].w, inv) & 255) << 24);
    out[i * 256 + t] = (int)p;
  }
}

// ---------------- i8 GEMM: 32x32x32 MFMA, 128x128 tile, 2-phase LDS dbuf ----------------
// C[M][N] = (A @ B^T) * sa[m]*sb[n]; A [M][4096] i8, B [N][4096] i8 row-major.
// BK=64B; 4 waves 2x2, wave-tile 64x64 (2x2 of 32x32). gridDim.y MUST be 16.
// XCD-aware swizzle: column-major decode so each XCD runs bx-strips (B-panel L2 reuse).
__global__ __launch_bounds__(256, 3) void k_gemm32(const signed char* __restrict__ A,
                                                   const float* __restrict__ sa,
                                                   const signed char* __restrict__ B,
                                                   const float* __restrict__ sb,
                                                   float* __restrict__ C, int N) {
  const int K = HDIM;
  int total = gridDim.x * 16;
  int id = blockIdx.y * gridDim.x + blockIdx.x;
  int nper = total >> 3;                       // total % 8 == 0 for all our launches
  int nid = (id & 7) * nper + (id >> 3);
  int m0 = (nid & 15) * 128;                   // by fastest -> same bx consecutive
  int n0 = (nid >> 4) * 128;

  int lane = threadIdx.x & 63, w = threadIdx.x >> 6;
  int wrb = (w >> 1) << 6;   // wave row base
  int wcb = (w & 1) << 6;    // wave col base
  __shared__ signed char Al[2][8192];
  __shared__ signed char Bl[2][8192];
  int srow = lane >> 2;                                  // staging: 4 lanes per 64B row
  int schunk = (((lane & 3) ^ ((lane >> 2) & 3)) << 4);  // pre-swizzled source chunk

  auto stage = [&](int buf, int k0) {
#pragma unroll
    for (int i = 0; i < 2; ++i) {
      int idx = w * 2 + i;
      int row = idx * 16 + srow;
      GLL16(A + (size_t)(m0 + row) * K + k0 + schunk, &Al[buf][idx * 1024]);
      GLL16(B + (size_t)(n0 + row) * K + k0 + schunk, &Bl[buf][idx * 1024]);
    }
  };

  v16i acc[2][2];
#pragma unroll
  for (int mt = 0; mt < 2; ++mt)
#pragma unroll
    for (int nt = 0; nt < 2; ++nt)
#pragma unroll
      for (int r = 0; r < 16; ++r) acc[mt][nt][r] = 0;

  stage(0, 0);
  __syncthreads();
  const int nk = K / 64;
  for (int t = 0; t < nk; ++t) {
    int pb = t & 1;
    if (t + 1 < nk) stage(pb ^ 1, (t + 1) * 64);
    const signed char* Ab = &Al[pb][0];
    const signed char* Bb = &Bl[pb][0];
#pragma unroll
    for (int kc = 0; kc < 2; ++kc) {
      int coff = kc * 32 + ((lane >> 5) * 16);
      v4i af[2], bf[2];
#pragma unroll
      for (int mt = 0; mt < 2; ++mt) {
        int row = wrb + mt * 32 + (lane & 31);
        af[mt] = *(const v4i*)(Ab + row * 64 + (coff ^ ((row & 3) << 4)));
      }
#pragma unroll
      for (int nt = 0; nt < 2; ++nt) {
        int row = wcb + nt * 32 + (lane & 31);
        bf[nt] = *(const v4i*)(Bb + row * 64 + (coff ^ ((row & 3) << 4)));
      }
#pragma unroll
      for (int mt = 0; mt < 2; ++mt)
#pragma unroll
        for (int nt = 0; nt < 2; ++nt)
          acc[mt][nt] = __builtin_amdgcn_mfma_i32_32x32x32_i8(af[mt], bf[nt], acc[mt][nt], 0, 0, 0);
    }
    __syncthreads();
  }

  // C/D 32x32 layout: col = lane&31, row = (r&3) + 8*(r>>2) + 4*(lane>>5)  [m74/m101]
  int cn = lane & 31, g4 = (lane >> 5) * 4;
#pragma unroll
  for (int mt = 0; mt < 2; ++mt)
#pragma unroll
    for (int nt = 0; nt < 2; ++nt) {
      int n = n0 + wcb + nt * 32 + cn;
      float sbn = sb[n];
#pragma unroll
      for (int r = 0; r < 16; ++r) {
        int m = m0 + wrb + mt * 32 + (r & 3) + 8 * (r >> 2) + g4;
        C[(size_t)m * N + n] = (float)acc[mt][nt][r] * sa[m] * sbn;
      }
    }
}

// ---------------- RoPE + per-128 fake-quant from fused QKV buffer ----------------
// src [S][QKVN] f32; head hh at cols colbase + hh*HD. dst [nh][S][HD] i8.
__global__ void k_rope_quant(const float* __restrict__ src, const float* __restrict__ ct,
                             const float* __restrict__ st, signed char* __restrict__ dst,
                             float* __restrict__ scales, int colbase) {
  int b = blockIdx.x;
  int hh = b >> 11;                // / S_LEN
  int s = b & (S_LEN - 1);
  int d = threadIdx.x;             // 0..63
  size_t base = (size_t)s * QKVN + colbase + (size_t)hh * HD;
  float x1 = src[base + d];
  float x2 = src[base + d + 64];
  float c = ct[(s << 6) + d], sn = st[(s << 6) + d];
  float o1 = x1 * c - x2 * sn;
  float o2 = x2 * c + x1 * sn;
  float am = fmaxf(fabsf(o1), fabsf(o2));
#pragma unroll
  for (int m = 1; m < 64; m <<= 1) am = fmaxf(am, __shfl_xor(am, m));
  float sc = fmaxf(am * (1.0f / 127.0f), 1e-8f);
  float inv = 1.0f / sc;
  if (d == 0) scales[hh * S_LEN + s] = sc;
  signed char* o = dst + ((size_t)hh * S_LEN + s) * HD;
  o[d] = (signed char)quant1(o1, inv);
  o[d + 64] = (signed char)quant1(o2, inv);
}

// ---------------- V: per-128 fake-quant, integers as bf16, TRANSPOSED [NKV][HD][S] ----------------
__global__ void k_quant_v(const float* __restrict__ src, short* __restrict__ vt,
                          float* __restrict__ sv) {
  int b = blockIdx.x;
  int hk = b >> 11;
  int s = b & (S_LEN - 1);
  int d = threadIdx.x;
  size_t base = (size_t)s * QKVN + 5120 + (size_t)hk * HD;
  float x1 = src[base + d];
  float x2 = src[base + d + 64];
  float am = fmaxf(fabsf(x1), fabsf(x2));
#pragma unroll
  for (int m = 1; m < 64; m <<= 1) am = fmaxf(am, __shfl_xor(am, m));
  float sc = fmaxf(am * (1.0f / 127.0f), 1e-8f);
  float inv = 1.0f / sc;
  if (d == 0) sv[hk * S_LEN + s] = sc;
  int q1i = quant1(x1, inv), q2i = quant1(x2, inv);
  size_t vb = (size_t)hk * HD * S_LEN;
  vt[vb + (size_t)d * S_LEN + s] = f32_bf16((float)q1i);          // exact: |int|<=128
  vt[vb + (size_t)(d + 64) * S_LEN + s] = f32_bf16((float)q2i);
}

// ---------------- attention: two-pass, K+V double-buffered, 1 barrier/tile ----------------
// grid (NH, 32); qt = 31 - by (LPT: longest blocks dispatch first).
// 4 waves; wave w owns q rows q0+16w..+15. K tile 64x128B dbuf, V tile 128x128B dbuf.
__global__ __launch_bounds__(256, 2) void k_attn(const signed char* __restrict__ qi8,
                                                 const float* __restrict__ sq,
                                                 const signed char* __restrict__ ki8,
                                                 const float* __restrict__ sk,
                                                 const short* __restrict__ vt,
                                                 const float* __restrict__ sv,
                                                 float* __restrict__ out) {
  int h = blockIdx.x;
  int qt = 31 - blockIdx.y;
  int hk = h >> 2;
  int lane = threadIdx.x & 63;
  int w = threadIdx.x >> 6;
  int q0 = qt * 64;
  int wrow0 = q0 + w * 16;

  __shared__ signed char Kl[2][8192];   // 16 KiB
  __shared__ short Vl[2][8192];         // 32 KiB, [d][kv_local] per buf
  __shared__ short wlds[4][1024];       // 8 KiB, per-wave P*sv tile

  const signed char* qbase = qi8 + (size_t)h * S_LEN * HD;
  const signed char* kbase = ki8 + (size_t)hk * S_LEN * HD;
  const char* vbase = (const char*)(vt + (size_t)hk * HD * S_LEN);
  const float* skh = sk + hk * S_LEN;
  const float* svh = sv + hk * S_LEN;

  // Q fragments: lane holds row lane&15, bytes ks*32+(lane>>4)*8
  long aq[4];
  {
    const signed char* qrow = qbase + (size_t)(wrow0 + (lane & 15)) * HD + ((lane >> 4) * 8);
#pragma unroll
    for (int ks = 0; ks < 4; ++ks) aq[ks] = *(const long*)(qrow + ks * 32);
  }
  int crow = (lane >> 4) * 4;
  int ccol = lane & 15;
  float sq2[4];
#pragma unroll
  for (int r = 0; r < 4; ++r)   // fold 1/sqrt(128) and log2(e): exp2 downstream
    sq2[r] = sq[h * S_LEN + wrow0 + crow + r] *
             (0.08838834764831843f * 1.4426950408889634f);

  int ntiles = qt + 1;
  int srow8 = lane >> 3;                          // staging: 8 lanes per 128B row
  int schunk = (((lane & 7) ^ srow8) << 4);       // pre-swizzled source chunk

  auto stageK = [&](int jt, int buf) {
    int j0 = jt * 64;
#pragma unroll
    for (int i = 0; i < 2; ++i) {
      int idx = w * 2 + i;
      int row = idx * 8 + srow8;
      GLL16(kbase + (size_t)(j0 + row) * HD + schunk, &Kl[buf][idx * 1024]);
    }
  };
  auto stageV = [&](int jt, int buf) {
    int j0 = jt * 64;
#pragma unroll
    for (int i = 0; i < 4; ++i) {
      int idx = w * 4 + i;
      int row = idx * 8 + srow8;
      GLL16(vbase + (size_t)row * (S_LEN * 2) + (size_t)j0 * 2 + schunk,
            (char*)&Vl[buf][0] + idx * 1024);
    }
  };

  // ---- PASS 1: exact row max (base-2-scaled scores) ----
  float mrow[4] = {-3e38f, -3e38f, -3e38f, -3e38f};
  stageK(0, 0);
  __syncthreads();
  for (int jt = 0; jt < ntiles; ++jt) {
    int pb = jt & 1;
    if (jt + 1 < ntiles) stageK(jt + 1, pb ^ 1);
    const signed char* Kb = &Kl[pb][0];
#pragma unroll
    for (int nt = 0; nt < 4; ++nt) {
      int jr = nt * 16 + ccol;
      const signed char* kr = Kb + jr * 128;
      v4i acc = {0, 0, 0, 0};
#pragma unroll
      for (int ks = 0; ks < 4; ++ks) {
        long b = *(const long*)(kr + ((ks * 32 + ((lane >> 4) * 8)) ^ ((jr & 7) << 4)));
        acc = __builtin_amdgcn_mfma_i32_16x16x32_i8(aq[ks], b, acc, 0, 0, 0);
      }
      int j = jt * 64 + jr;
      float skj = skh[j];
      if (jt == ntiles - 1) {
#pragma unroll
        for (int r = 0; r < 4; ++r)
          if (j <= wrow0 + crow + r)
            mrow[r] = fmaxf(mrow[r], (float)acc[r] * sq2[r] * skj);
      } else {
#pragma unroll
        for (int r = 0; r < 4; ++r)
          mrow[r] = fmaxf(mrow[r], (float)acc[r] * sq2[r] * skj);
      }
    }
    __syncthreads();
  }
#pragma unroll
  for (int r = 0; r < 4; ++r) {
    float v = mrow[r];
    v = fmaxf(v, __shfl_xor(v, 1));
    v = fmaxf(v, __shfl_xor(v, 2));
    v = fmaxf(v, __shfl_xor(v, 4));
    v = fmaxf(v, __shfl_xor(v, 8));
    mrow[r] = v;
  }

  // ---- PASS 2: p_int = rint(127*2^(s2-m2)); Z accumulate; PV via bf16 MFMA ----
  float Z[4] = {0.f, 0.f, 0.f, 0.f};
  v4f accp[8];
  v4f zf = {0.f, 0.f, 0.f, 0.f};
#pragma unroll
  for (int dt = 0; dt < 8; ++dt) accp[dt] = zf;

  stageK(0, 0);
  stageV(0, 0);
  __syncthreads();
  for (int jt = 0; jt < ntiles; ++jt) {
    int pb = jt & 1;
    if (jt + 1 < ntiles) {
      stageK(jt + 1, pb ^ 1);
      stageV(jt + 1, pb ^ 1);
    }
    const signed char* Kb = &Kl[pb][0];
#pragma unroll
    for (int nt = 0; nt < 4; ++nt) {
      int jr = nt * 16 + ccol;
      const signed char* kr = Kb + jr * 128;
      v4i acc = {0, 0, 0, 0};
#pragma unroll
      for (int ks = 0; ks < 4; ++ks) {
        long b = *(const long*)(kr + ((ks * 32 + ((lane >> 4) * 8)) ^ ((jr & 7) << 4)));
        acc = __builtin_amdgcn_mfma_i32_16x16x32_i8(aq[ks], b, acc, 0, 0, 0);
      }
      int j = jt * 64 + jr;
      float skj = skh[j];
      float svj = svh[j];
      if (jt == ntiles - 1) {
#pragma unroll
        for (int r = 0; r < 4; ++r) {
          int row = crow + r;
          float e = (j <= wrow0 + row)
                        ? exp2f((float)acc[r] * sq2[r] * skj - mrow[r]) : 0.f;
          Z[r] += e;
          float wv = rintf(127.0f * e) * svj;
          int idx = ((row << 6) | (nt * 16 + ccol)) ^ ((row & 7) << 3);
          wlds[w][idx] = f32_bf16(wv);
        }
      } else {
#pragma unroll
        for (int r = 0; r < 4; ++r) {
          int row = crow + r;
          float e = exp2f((float)acc[r] * sq2[r] * skj - mrow[r]);
          Z[r] += e;
          float wv = rintf(127.0f * e) * svj;
          int idx = ((row << 6) | (nt * 16 + ccol)) ^ ((row & 7) << 3);
          wlds[w][idx] = f32_bf16(wv);
        }
      }
    }
    // PV: A from wlds (same-wave lgkm ordering), B from Vl[pb]
    const short* Vb = &Vl[pb][0];
#pragma unroll
    for (int ks2 = 0; ks2 < 2; ++ks2) {
      int bels = (((lane & 15) << 6) + ks2 * 32 + ((lane >> 4) * 8)) ^ ((lane & 7) << 3);
      v8s aw = *(const v8s*)&wlds[w][bels];
#pragma unroll
      for (int dt = 0; dt < 8; ++dt) {
        int d = dt * 16 + (lane & 15);
        int off = (ks2 * 64 + ((lane >> 4) << 4)) ^ ((d & 7) << 4);
        v8s bv = *(const v8s*)((const char*)Vb + d * 128 + off);
        accp[dt] = __builtin_amdgcn_mfma_f32_16x16x32_bf16(aw, bv, accp[dt], 0, 0, 0);
      }
    }
    __syncthreads();
  }

#pragma unroll
  for (int r = 0; r < 4; ++r) {
    float v = Z[r];
    v += __shfl_xor(v, 1);
    v += __shfl_xor(v, 2);
    v += __shfl_xor(v, 4);
    v += __shfl_xor(v, 8);
    Z[r] = 1.0f / (127.0f * v);
  }
#pragma unroll
  for (int dt = 0; dt < 8; ++dt)
#pragma unroll
    for (int r = 0; r < 4; ++r) {
      int i = wrow0 + crow + r;
      int d = dt * 16 + ccol;
      out[(size_t)i * HDIM + (size_t)h * HD + d] = accp[dt][r] * Z[r];
    }
}

// ------------------------------------------------------------------
extern "C" void kernel_launch(void* const* d_in, const int* in_sizes, int n_in,
                              void* d_out, int out_size, void* d_ws, size_t ws_size,
                              hipStream_t stream) {
  const float* x  = (const float*)d_in[0];
  // d_in[1] attention_mask: causal, applied analytically. d_in[2] position_ids: arange.
  const float* Wq = (const float*)d_in[3];
  const float* Wk = (const float*)d_in[4];
  const float* Wv = (const float*)d_in[5];
  const float* Wo = (const float*)d_in[6];

  char* p = (char*)d_ws;
  auto alloc = [&](size_t sz) { char* r = p; p += (sz + 255) & ~(size_t)255; return r; };
  signed char* QX   = (signed char*)alloc((size_t)S_LEN * HDIM);       // 8 MiB
  float* SX         = (float*)alloc(S_LEN * 4);
  signed char* WQKV = (signed char*)alloc((size_t)QKVN * HDIM);        // 24 MiB
  float* SQKV       = (float*)alloc(QKVN * 4);
  signed char* WOI  = (signed char*)alloc((size_t)HDIM * HDIM);        // 16 MiB
  float* SWO        = (float*)alloc(HDIM * 4);
  float* QKVF       = (float*)alloc((size_t)S_LEN * QKVN * 4);         // 48 MiB
  signed char* QI8  = (signed char*)alloc((size_t)NH * S_LEN * HD);    // 8 MiB
  float* SQ         = (float*)alloc(NH * S_LEN * 4);
  signed char* KI8  = (signed char*)alloc((size_t)NKV * S_LEN * HD);   // 2 MiB
  float* SK         = (float*)alloc(NKV * S_LEN * 4);
  short* VT         = (short*)alloc((size_t)NKV * HD * S_LEN * 2);     // 4 MiB
  float* SV         = (float*)alloc(NKV * S_LEN * 4);
  float* CT         = (float*)alloc(S_LEN * 64 * 4);
  float* ST         = (float*)alloc(S_LEN * 64 * 4);
  float* SA         = (float*)alloc(S_LEN * 4);
  // aliases (lifetimes disjoint): attn output reuses QKVF; attn-quant i8 reuses QX
  float* ATTNF     = QKVF;
  signed char* AI8 = QX;

  k_rope_tables<<<(S_LEN * 64 + 255) / 256, 256, 0, stream>>>(CT, ST);

  k_quant_rows<<<S_LEN, 256, 0, stream>>>(x, QX, SX);
  k_quant_rows<<<HDIM, 256, 0, stream>>>(Wq, WQKV, SQKV);
  k_quant_rows<<<KVD, 256, 0, stream>>>(Wk, WQKV + (size_t)4096 * HDIM, SQKV + 4096);
  k_quant_rows<<<KVD, 256, 0, stream>>>(Wv, WQKV + (size_t)5120 * HDIM, SQKV + 5120);
  k_quant_rows<<<HDIM, 256, 0, stream>>>(Wo, WOI, SWO);

  // fused QKV projection: [2048][6144] = X @ WQKV^T
  k_gemm32<<<dim3(QKVN / 128, S_LEN / 128), 256, 0, stream>>>(QX, SX, WQKV, SQKV, QKVF, QKVN);

  k_rope_quant<<<NH * S_LEN, 64, 0, stream>>>(QKVF, CT, ST, QI8, SQ, 0);
  k_rope_quant<<<NKV * S_LEN, 64, 0, stream>>>(QKVF, CT, ST, KI8, SK, 4096);
  k_quant_v<<<NKV * S_LEN, 64, 0, stream>>>(QKVF, VT, SV);

  k_attn<<<dim3(NH, 32), 256, 0, stream>>>(QI8, SQ, KI8, SK, VT, SV, ATTNF);

  k_quant_rows<<<S_LEN, 256, 0, stream>>>(ATTNF, AI8, SA);
  k_gemm32<<<dim3(HDIM / 128, S_LEN / 128), 256, 0, stream>>>(AI8, SA, WOI, SWO,
                                                              (float*)d_out, HDIM);
}